// Round 16
// baseline (207.490 us; speedup 1.0000x reference)
//
#include <hip/hip_runtime.h>

// MiniAttentionLayer fused kernel for MI355X (gfx950).
//
// ROUND 16: R15's restructure (1024x128 blocks, 4 barrier domains/CU, Qm
// direct from L2, Wnv/Wev via async global_load_lds) failed because the
// phase-2 staging loop covered only HALF the chunk: 768 16B-segments needed
// (Wnv 4096 + Wev 2048 shorts), but 3 iters x 128 threads = 384 staged ->
// v-GEMM read stale LDS for half its K-range. FIX: 6 iterations (seg<512 ->
// Wnv, else Wev), prologue and per-chunk. Everything else R15-identical.
// Q-GEMM bytes identical to R11's LDS copy -> absmax must return to bitwise
// 6.103516e-05. Preps R14 VERBATIM.
//
//   score[h,s]*16 = x_e^T M_{h,s} x_s ; softmax -> attn
//   M^n_h = F_h^T @ (Wk_h @ Wn_k) ; M^e_h = F_h^T @ (Wk_h @ We_k) ; F = Wq@We_q
//   vbar_h = sum_s attn[h,s] v_s ; v_s = W*_v x_s (+ b*_v)
//   h1pre = Qm @ [vbar_0|vbar_1] + c2 ; Qm_h = P @ Wv_h ; P = W1@Wo
//   out = W2 @ silu(h1pre) + b2

#define TPB 128

typedef __attribute__((ext_vector_type(8))) short bf16x8;
typedef __attribute__((ext_vector_type(4))) float f32x4;
typedef unsigned int u32;

__device__ __forceinline__ unsigned short f2bf(float f) {
  union { float f; unsigned u; } v; v.f = f;
  unsigned r = v.u + 0x7FFFu + ((v.u >> 16) & 1u);  // RNE
  return (unsigned short)(r >> 16);
}
__device__ __forceinline__ float bf2f(unsigned short h) {
  union { unsigned u; float f; } v; v.u = ((unsigned)h) << 16;
  return v.f;
}
__device__ __forceinline__ f32x4 mfma16(bf16x8 a, bf16x8 b, f32x4 c) {
  return __builtin_amdgcn_mfma_f32_16x16x32_bf16(a, b, c, 0, 0, 0);
}
__device__ __forceinline__ bf16x8 pack8(const float* __restrict__ p) {
  float4 a = *(const float4*)p;
  float4 b = *(const float4*)(p + 4);
  bf16x8 r;
  r[0] = (short)f2bf(a.x); r[1] = (short)f2bf(a.y);
  r[2] = (short)f2bf(a.z); r[3] = (short)f2bf(a.w);
  r[4] = (short)f2bf(b.x); r[5] = (short)f2bf(b.y);
  r[6] = (short)f2bf(b.z); r[7] = (short)f2bf(b.w);
  return r;
}
// async global->LDS, 16B per lane (dest linear: base + lane*16)
__device__ __forceinline__ void gld16(const unsigned short* g, unsigned short* l) {
  __builtin_amdgcn_global_load_lds(
      (const __attribute__((address_space(1))) u32*)g,
      (__attribute__((address_space(3))) u32*)l, 16, 0, 0);
}
// fragment-tiled offset: element (lr = B-col within 16-tile, k) -> tiled index
__device__ __forceinline__ int fragoff(int lr, int k) {
  return (k >> 5) * 512 + ((k >> 3) & 3) * 128 + lr * 8 + (k & 7);
}

// Double-buffered LDS-tiled prep GEMM (R14 VERBATIM, 256-thread blocks)
__device__ __forceinline__ void gemm44d(const float* __restrict__ A0, int lda,
                                        const float* __restrict__ Bb, int ldb,
                                        int K, int tid, int tn,
                                        float (&acc)[4][4], float (*Bs)[132]) {
  const int row = tid >> 4;
  const int col = (tid & 15) * 8;
  {
    const float* src = Bb + (size_t)row * ldb + col;
    float4 v0 = *(const float4*)(src);
    float4 v1 = *(const float4*)(src + 4);
    *(float4*)&Bs[row][col] = v0;
    *(float4*)&Bs[row][col + 4] = v1;
  }
  __syncthreads();
  const int nsteps = K >> 4;
  for (int s = 0; s < nsteps; ++s) {
    const bool more = (s + 1 < nsteps);
    float4 v0, v1;
    if (more) {
      const float* src = Bb + (size_t)((s + 1) * 16 + row) * ldb + col;
      v0 = *(const float4*)(src);
      v1 = *(const float4*)(src + 4);
    }
    float (*Bcur)[132] = Bs + (s & 1) * 16;
    const int k0 = s * 16;
    float a_[4][16];
#pragma unroll
    for (int mi = 0; mi < 4; ++mi)
#pragma unroll
      for (int kq = 0; kq < 4; ++kq) {
        float4 t = *(const float4*)(A0 + mi * lda + k0 + kq * 4);
        a_[mi][kq * 4 + 0] = t.x; a_[mi][kq * 4 + 1] = t.y;
        a_[mi][kq * 4 + 2] = t.z; a_[mi][kq * 4 + 3] = t.w;
      }
#pragma unroll
    for (int kk = 0; kk < 16; ++kk) {
      float4 bv = *(const float4*)&Bcur[kk][tn * 4];
#pragma unroll
      for (int mi = 0; mi < 4; ++mi) {
        acc[mi][0] += a_[mi][kk] * bv.x;
        acc[mi][1] += a_[mi][kk] * bv.y;
        acc[mi][2] += a_[mi][kk] * bv.z;
        acc[mi][3] += a_[mi][kk] * bv.w;
      }
    }
    if (more) {
      float (*Bnxt)[132] = Bs + ((s + 1) & 1) * 16;
      *(float4*)&Bnxt[row][col] = v0;
      *(float4*)&Bnxt[row][col + 4] = v1;
    }
    __syncthreads();
  }
}

// ---------------------------------------------------------------------------
// prep1 (R14 VERBATIM): F->FT ; P ; Kn_h ; Ke_h ; WnvT/WevT/W2bT casts.
// ---------------------------------------------------------------------------
__global__ void prep1(const float* __restrict__ Wn, const float* __restrict__ We,
                      const float* __restrict__ Wi, const float* __restrict__ Wo,
                      const float* __restrict__ W1, const float* __restrict__ W2,
                      float* __restrict__ FT, float* __restrict__ P,
                      float* __restrict__ Kn, float* __restrict__ Ke,
                      unsigned short* __restrict__ WnvT, unsigned short* __restrict__ WevT,
                      unsigned short* __restrict__ W2bT) {
  __shared__ float Bs[32][132];
  const int bid = blockIdx.x, tid = threadIdx.x;
  const int tm = tid >> 5, tn = tid & 31;
  if (bid < 16) {                           // F [512,128] K=512 -> FT[n][m]
    int m = bid * 32 + tm * 4, n0 = tn * 4;
    float acc[4][4] = {};
    gemm44d(Wi + m * 512, 512, We, 128, 512, tid, tn, acc, Bs);
#pragma unroll
    for (int mi = 0; mi < 4; ++mi)
#pragma unroll
      for (int ni = 0; ni < 4; ++ni) FT[(n0 + ni) * 512 + m + mi] = acc[mi][ni];
  } else if (bid < 48) {                    // P [256,512] K=512
    int b = bid - 16; int m = (b >> 2) * 32 + tm * 4, n0 = (b & 3) * 128 + tn * 4;
    float acc[4][4] = {};
    gemm44d(W1 + m * 512, 512, Wo + (b & 3) * 128, 512, 512, tid, tn, acc, Bs);
#pragma unroll
    for (int mi = 0; mi < 4; ++mi)
#pragma unroll
      for (int ni = 0; ni < 4; ++ni) P[(m + mi) * 512 + n0 + ni] = acc[mi][ni];
  } else if (bid < 80) {                    // Kn_h [256,256] K=512
    int b = bid - 48; int h = b >> 4, r = b & 15;
    int c = (r >> 1) * 32 + tm * 4, b0 = (r & 1) * 128 + tn * 4;
    float acc[4][4] = {};
    gemm44d(Wi + (size_t)(512 + h * 256 + c) * 512, 512, Wn + 512 * 256 + (r & 1) * 128, 256, 512,
            tid, tn, acc, Bs);
#pragma unroll
    for (int mi = 0; mi < 4; ++mi)
#pragma unroll
      for (int ni = 0; ni < 4; ++ni) Kn[h * 65536 + (c + mi) * 256 + b0 + ni] = acc[mi][ni];
  } else if (bid < 96) {                    // Ke_h [256,128] K=512
    int b = bid - 80; int h = b >> 3, r = b & 7;
    int c = r * 32 + tm * 4, b0 = tn * 4;
    float acc[4][4] = {};
    gemm44d(Wi + (size_t)(512 + h * 256 + c) * 512, 512, We + 512 * 128, 128, 512, tid, tn, acc, Bs);
#pragma unroll
    for (int mi = 0; mi < 4; ++mi)
#pragma unroll
      for (int ni = 0; ni < 4; ++ni) Ke[h * 32768 + (c + mi) * 128 + b0 + ni] = acc[mi][ni];
  } else if (bid < 224) {                   // Wn_v -> bf16 TILED
    int i = ((bid - 96) * 256 + tid) * 4;
#pragma unroll
    for (int t = 0; t < 4; ++t) {
      int ii = i + t; int vrow = ii >> 8, k = ii & 255;
      WnvT[(vrow >> 4) * 4096 + fragoff(vrow & 15, k)] = f2bf(Wn[262144 + ii]);
    }
  } else if (bid < 288) {                   // We_v -> bf16 TILED
    int i = ((bid - 224) * 256 + tid) * 4;
#pragma unroll
    for (int t = 0; t < 4; ++t) {
      int ii = i + t; int vrow = ii >> 7, k = ii & 127;
      WevT[(vrow >> 4) * 2048 + fragoff(vrow & 15, k)] = f2bf(We[131072 + ii]);
    }
  } else {                                  // W2 -> bf16 TILED
    int i = ((bid - 288) * 256 + tid) * 4;
#pragma unroll
    for (int t = 0; t < 4; ++t) {
      int ii = i + t; int o = ii >> 8, k = ii & 255;
      W2bT[(k >> 6) * 8192 + ((k >> 5) & 1) * 4096 + (o >> 4) * 512 + fragoff(o & 15, k & 31)] =
          f2bf(W2[ii]);
    }
  }
}

// ---------------------------------------------------------------------------
// prep2 (R14 VERBATIM): MtnT ; MteT ; QmT ; c2.
// ---------------------------------------------------------------------------
__global__ void prep2(const float* __restrict__ Wi, const float* __restrict__ W1,
                      const float* __restrict__ bi, const float* __restrict__ bo,
                      const float* __restrict__ b1,
                      const float* __restrict__ FT, const float* __restrict__ P,
                      const float* __restrict__ Kn, const float* __restrict__ Ke,
                      unsigned short* __restrict__ MtnT, unsigned short* __restrict__ MteT,
                      unsigned short* __restrict__ QmT, float* __restrict__ c2) {
  __shared__ float Bs[32][132];
  const int bid = blockIdx.x, tid = threadIdx.x;
  const int tm = tid >> 5, tn = tid & 31;
  if (bid < 16) {                           // Mtn_h [128,256] K=256
    int h = bid >> 3, r = bid & 7;
    int a = (r >> 1) * 32 + tm * 4, b0 = (r & 1) * 128 + tn * 4;
    float acc[4][4] = {};
    gemm44d(FT + a * 512 + h * 256, 512, Kn + h * 65536 + (r & 1) * 128, 256, 256, tid, tn, acc, Bs);
#pragma unroll
    for (int mi = 0; mi < 4; ++mi)
#pragma unroll
      for (int ni = 0; ni < 4; ++ni) {
        int aa = a + mi, bb = b0 + ni;
        MtnT[(h * 2 + (bb >> 7)) * 16384 + ((bb >> 5) & 3) * 4096 + ((bb >> 4) & 1) * 2048 +
             fragoff(bb & 15, aa)] = f2bf(acc[mi][ni]);
      }
  } else if (bid < 24) {                    // Mte_h [128,128] K=256
    int b = bid - 16; int h = b >> 2, r = b & 3;
    int a = r * 32 + tm * 4, b0 = tn * 4;
    float acc[4][4] = {};
    gemm44d(FT + a * 512 + h * 256, 512, Ke + h * 32768, 128, 256, tid, tn, acc, Bs);
#pragma unroll
    for (int mi = 0; mi < 4; ++mi)
#pragma unroll
      for (int ni = 0; ni < 4; ++ni) {
        int aa = a + mi, bb = b0 + ni;
        MteT[h * 16384 + ((bb >> 5) & 3) * 4096 + ((bb >> 4) & 1) * 2048 +
             fragoff(bb & 15, aa)] = f2bf(acc[mi][ni]);
      }
  } else if (bid < 88) {                    // Qm_h [256,512] K=256
    int b = bid - 24; int h = b >> 5, r = b & 31;
    int i = (r >> 2) * 32 + tm * 4, t0 = (r & 3) * 128 + tn * 4;
    float acc[4][4] = {};
    gemm44d(P + i * 512 + h * 256, 512, Wi + (size_t)(1024 + h * 256) * 512 + (r & 3) * 128, 512,
            256, tid, tn, acc, Bs);
#pragma unroll
    for (int mi = 0; mi < 4; ++mi)
#pragma unroll
      for (int ni = 0; ni < 4; ++ni) {
        int ii = i + mi, tt = t0 + ni;
        QmT[(tt >> 5) * 16384 + h * 8192 + (ii >> 4) * 512 + fragoff(ii & 15, tt & 31)] =
            f2bf(acc[mi][ni]);
      }
  } else {                                  // c2
    float s0 = 0.f, s1 = 0.f, s2 = 0.f, s3 = 0.f;
    for (int c = 0; c < 512; c += 4) {
      float4 p = *(const float4*)(P + tid * 512 + c);
      float4 w = *(const float4*)(W1 + tid * 512 + c);
      float4 bv = *(const float4*)(bi + 1024 + c);
      float4 bw = *(const float4*)(bo + c);
      s0 += p.x * bv.x + w.x * bw.x;
      s1 += p.y * bv.y + w.y * bw.y;
      s2 += p.z * bv.z + w.z * bw.z;
      s3 += p.w * bv.w + w.w * bw.w;
    }
    c2[tid] = b1[tid] + (s0 + s1) + (s2 + s3);
  }
}

// ---------------------------------------------------------------------------
// Fused helpers — 128-thread async staging (32KB slice = 2048 segs, 16/thread)
// ---------------------------------------------------------------------------
__device__ __forceinline__ void stage32k_async(unsigned short* lds,
                                               const unsigned short* __restrict__ src, int tid) {
#pragma unroll
  for (int i = 0; i < 16; ++i) {
    int seg = i * 128 + tid;
    gld16(src + seg * 8, lds + seg * 8);
  }
}

template <int AOFS>
__device__ __forceinline__ void p1n(const unsigned short* __restrict__ srcT,
                                    unsigned short* sflat, unsigned short (&tb)[16][40],
                                    const bf16x8 (&au)[8], const bf16x8 (&av)[8],
                                    const bf16x8 (&ae)[4], int tid, int lrow, int lgrp,
                                    float& su, float& sv) {
  stage32k_async(sflat, srcT, tid);
  __syncthreads();                    // vmcnt drain completes async loads
  const int lane8 = (lgrp * 16 + lrow) * 8;
#pragma unroll
  for (int c = 0; c < 4; ++c) {
    f32x4 acc0 = {0.f, 0.f, 0.f, 0.f}, acc1 = {0.f, 0.f, 0.f, 0.f};
#pragma unroll
    for (int kt = 0; kt < 4; ++kt) {
      bf16x8 b0 = *(bf16x8*)(sflat + c * 4096 + kt * 512 + lane8);
      bf16x8 b1f = *(bf16x8*)(sflat + c * 4096 + 2048 + kt * 512 + lane8);
      acc0 = mfma16(ae[kt], b0, acc0);
      acc1 = mfma16(ae[kt], b1f, acc1);
    }
#pragma unroll
    for (int j = 0; j < 4; ++j) {
      tb[lgrp * 4 + j][lrow] = f2bf(acc0[j]);
      tb[lgrp * 4 + j][16 + lrow] = f2bf(acc1[j]);
    }
    bf16x8 y = *(bf16x8*)&tb[lrow][lgrp * 8];
#pragma unroll
    for (int j = 0; j < 8; ++j) {
      float yf = bf2f((unsigned short)y[j]);
      su += yf * bf2f((unsigned short)au[AOFS + c][j]);
      sv += yf * bf2f((unsigned short)av[AOFS + c][j]);
    }
  }
  __syncthreads();
}

__device__ __forceinline__ void p1e(const unsigned short* __restrict__ srcT,
                                    unsigned short* sflat, unsigned short (&tb)[16][40],
                                    const bf16x8 (&ae)[4], int tid, int lrow, int lgrp,
                                    float& se) {
  stage32k_async(sflat, srcT, tid);
  __syncthreads();
  const int lane8 = (lgrp * 16 + lrow) * 8;
#pragma unroll
  for (int c = 0; c < 4; ++c) {
    f32x4 acc0 = {0.f, 0.f, 0.f, 0.f}, acc1 = {0.f, 0.f, 0.f, 0.f};
#pragma unroll
    for (int kt = 0; kt < 4; ++kt) {
      bf16x8 b0 = *(bf16x8*)(sflat + c * 4096 + kt * 512 + lane8);
      bf16x8 b1f = *(bf16x8*)(sflat + c * 4096 + 2048 + kt * 512 + lane8);
      acc0 = mfma16(ae[kt], b0, acc0);
      acc1 = mfma16(ae[kt], b1f, acc1);
    }
#pragma unroll
    for (int j = 0; j < 4; ++j) {
      tb[lgrp * 4 + j][lrow] = f2bf(acc0[j]);
      tb[lgrp * 4 + j][16 + lrow] = f2bf(acc1[j]);
    }
    bf16x8 y = *(bf16x8*)&tb[lrow][lgrp * 8];
#pragma unroll
    for (int j = 0; j < 8; ++j)
      se += bf2f((unsigned short)y[j]) * bf2f((unsigned short)ae[c][j]);
  }
  __syncthreads();
}

// ---------------------------------------------------------------------------
// Fused main kernel: 1024 blocks x 128 threads (2 waves x 16 rows).
// Phase 2: Wnv/Wev async-dbuf (1 barrier/chunk); Qm direct from L2.
// ---------------------------------------------------------------------------
__global__ __launch_bounds__(TPB, 2) void fused_kernel(
    const float* __restrict__ Xu, const float* __restrict__ Xv, const float* __restrict__ Xe,
    const float* __restrict__ bn, const float* __restrict__ be, const float* __restrict__ b2,
    const unsigned short* __restrict__ MtnT, const unsigned short* __restrict__ MteT,
    const unsigned short* __restrict__ WnvT, const unsigned short* __restrict__ WevT,
    const unsigned short* __restrict__ QmT, const unsigned short* __restrict__ W2bT,
    const float* __restrict__ c2, float* __restrict__ Out) {
  // sStage: 32KB. Phase 2 uses [0,6144) and [6144,12288) as Wnv/Wev dbuf.
  __shared__ unsigned short sStage[16384];          // 32 KB
  __shared__ unsigned short sTbuf[2][2][16][40];    // 5 KB wave-local bounce
  __shared__ float sAttn[2][16][8];                 // 1 KB

  const int tid = threadIdx.x;
  const int wave = tid >> 6;
  const int lane = tid & 63;
  const int lrow = lane & 15, lgrp = lane >> 4;
  const int lane8 = lane * 8;
  const int r0 = blockIdx.x * 32 + wave * 16;

  // ---- A fragments (rows of this wave), fp32 -> bf16 ----
  bf16x8 au[8], av[8], ae[4];
  {
    const float* xu = Xu + (size_t)(r0 + lrow) * 256;
    const float* xv = Xv + (size_t)(r0 + lrow) * 256;
    const float* xe = Xe + (size_t)(r0 + lrow) * 128;
#pragma unroll
    for (int kt = 0; kt < 8; ++kt) {
      int off = kt * 32 + lgrp * 8;
      au[kt] = pack8(xu + off);
      av[kt] = pack8(xv + off);
    }
#pragma unroll
    for (int kt = 0; kt < 4; ++kt) ae[kt] = pack8(xe + kt * 32 + lgrp * 8);
  }

  // ================= Phase 1: scores (6 staged 32KB slices) =================
  float su0 = 0.f, sv0 = 0.f, se0 = 0.f, su1 = 0.f, sv1 = 0.f, se1 = 0.f;
  p1n<0>(MtnT,          sStage, sTbuf[wave][0], au, av, ae, tid, lrow, lgrp, su0, sv0);
  p1n<4>(MtnT + 16384,  sStage, sTbuf[wave][0], au, av, ae, tid, lrow, lgrp, su0, sv0);
  p1n<0>(MtnT + 32768,  sStage, sTbuf[wave][0], au, av, ae, tid, lrow, lgrp, su1, sv1);
  p1n<4>(MtnT + 49152,  sStage, sTbuf[wave][0], au, av, ae, tid, lrow, lgrp, su1, sv1);
  p1e(MteT,          sStage, sTbuf[wave][0], ae, tid, lrow, lgrp, se0);
  p1e(MteT + 16384,  sStage, sTbuf[wave][0], ae, tid, lrow, lgrp, se1);

  su0 += __shfl_xor(su0, 16); su0 += __shfl_xor(su0, 32);
  sv0 += __shfl_xor(sv0, 16); sv0 += __shfl_xor(sv0, 32);
  se0 += __shfl_xor(se0, 16); se0 += __shfl_xor(se0, 32);
  su1 += __shfl_xor(su1, 16); su1 += __shfl_xor(su1, 32);
  sv1 += __shfl_xor(sv1, 16); sv1 += __shfl_xor(sv1, 32);
  se1 += __shfl_xor(se1, 16); se1 += __shfl_xor(se1, 32);
  if (lane < 16) {
    sAttn[wave][lrow][0] = su0; sAttn[wave][lrow][1] = sv0; sAttn[wave][lrow][2] = se0;
    sAttn[wave][lrow][3] = su1; sAttn[wave][lrow][4] = sv1; sAttn[wave][lrow][5] = se1;
  }
  // softmax over s (scale 1/16); wave-local
  if (lane < 16) {
#pragma unroll
    for (int h = 0; h < 2; ++h) {
      float s0 = sAttn[wave][lrow][h * 3 + 0] * 0.0625f;
      float s1 = sAttn[wave][lrow][h * 3 + 1] * 0.0625f;
      float s2 = sAttn[wave][lrow][h * 3 + 2] * 0.0625f;
      float m = fmaxf(s0, fmaxf(s1, s2));
      float e0 = __expf(s0 - m), e1 = __expf(s1 - m), e2 = __expf(s2 - m);
      float inv = 1.f / (e0 + e1 + e2);
      sAttn[wave][lrow][h * 3 + 0] = e0 * inv;
      sAttn[wave][lrow][h * 3 + 1] = e1 * inv;
      sAttn[wave][lrow][h * 3 + 2] = e2 * inv;
    }
  }

  // ================= Phase 2: v-GEMM + vbar + Q-GEMM(L2-direct) =============
  f32x4 h1acc[16];
#pragma unroll
  for (int i = 0; i < 16; ++i) h1acc[i] = (f32x4){0.f, 0.f, 0.f, 0.f};

  // prologue: buf0 = {Wnv(0), Wev(0)} async. 768 16B-segments = 6 per thread.
  {
#pragma unroll
    for (int i = 0; i < 6; ++i) {
      int seg = i * 128 + tid;
      if (seg < 512) gld16(WnvT + seg * 8, sStage + seg * 8);
      else           gld16(WevT + (seg - 512) * 8, sStage + seg * 8);
    }
  }
  __syncthreads();

#pragma unroll 1
  for (int t = 0; t < 32; ++t) {
    unsigned short* wb = sStage + (t & 1) * 6144;
    unsigned short* nb = sStage + ((t & 1) ^ 1) * 6144;
    // async: Wnv/Wev of chunk t+1 -> nb (768 segs = 6/thread; nb unread during
    // t; loads drained by this chunk's end barrier)
    if (t < 31) {
      const int cn = t + 1;
#pragma unroll
      for (int i = 0; i < 6; ++i) {
        int seg = i * 128 + tid;
        if (seg < 512) gld16(WnvT + cn * 4096 + seg * 8, nb + seg * 8);
        else           gld16(WevT + cn * 2048 + (seg - 512) * 8, nb + seg * 8);
      }
    }

    // v-GEMM on wb
    f32x4 vu = {0.f, 0.f, 0.f, 0.f}, vv = {0.f, 0.f, 0.f, 0.f}, ve = {0.f, 0.f, 0.f, 0.f};
#pragma unroll
    for (int kt = 0; kt < 8; ++kt) {
      bf16x8 b = *(bf16x8*)(wb + kt * 512 + lane8);
      vu = mfma16(au[kt], b, vu);
      vv = mfma16(av[kt], b, vv);
    }
#pragma unroll
    for (int kt = 0; kt < 4; ++kt) {
      bf16x8 b = *(bf16x8*)(wb + 4096 + kt * 512 + lane8);
      ve = mfma16(ae[kt], b, ve);
    }
    // combine -> sTbuf (col offset by parity)
    const int vrow = t * 16 + lrow;
    const float bnv = bn[1024 + vrow], bev = be[1024 + vrow];
#pragma unroll
    for (int j = 0; j < 4; ++j) {
      const float* ar = &sAttn[wave][lgrp * 4 + j][0];
#pragma unroll
      for (int h = 0; h < 2; ++h) {
        float a0 = ar[h * 3 + 0], a1 = ar[h * 3 + 1], a2 = ar[h * 3 + 2];
        float vb = a0 * vu[j] + a1 * vv[j] + a2 * ve[j] + (a0 + a1) * bnv + a2 * bev;
        sTbuf[wave][h][lgrp * 4 + j][(t & 1) * 16 + lrow] = f2bf(vb);
      }
    }

    if (t & 1) {  // Q-GEMM over completed 32-col pair; Qm direct from L2
      const unsigned short* qbase = QmT + (size_t)(t >> 1) * 16384;
#pragma unroll
      for (int h2 = 0; h2 < 2; ++h2) {
        const unsigned short* qb = qbase + h2 * 8192;
        bf16x8 vbx = *(bf16x8*)&sTbuf[wave][h2][lrow][lgrp * 8];
#pragma unroll
        for (int g = 0; g < 4; ++g) {
          bf16x8 bq0 = *(const bf16x8*)(qb + (g * 4 + 0) * 512 + lane8);
          bf16x8 bq1 = *(const bf16x8*)(qb + (g * 4 + 1) * 512 + lane8);
          bf16x8 bq2 = *(const bf16x8*)(qb + (g * 4 + 2) * 512 + lane8);
          bf16x8 bq3 = *(const bf16x8*)(qb + (g * 4 + 3) * 512 + lane8);
          h1acc[g * 4 + 0] = mfma16(vbx, bq0, h1acc[g * 4 + 0]);
          h1acc[g * 4 + 1] = mfma16(vbx, bq1, h1acc[g * 4 + 1]);
          h1acc[g * 4 + 2] = mfma16(vbx, bq2, h1acc[g * 4 + 2]);
          h1acc[g * 4 + 3] = mfma16(vbx, bq3, h1acc[g * 4 + 3]);
        }
      }
    }
    __syncthreads();  // publishes nb's async loads; orders next chunk's reads
  }

  // ================= Phase 3: silu + W2 (2 staged 32KB halves) ==============
  f32x4 outacc[8];
#pragma unroll
  for (int i = 0; i < 8; ++i) outacc[i] = (f32x4){0.f, 0.f, 0.f, 0.f};

#pragma unroll
  for (int hh = 0; hh < 2; ++hh) {
    if (hh) __syncthreads();  // protect previous half's reads
    stage32k_async(sStage, W2bT + hh * 16384, tid);
    __syncthreads();
#pragma unroll
    for (int kc = 0; kc < 2; ++kc) {
      const int kg = hh * 2 + kc;
#pragma unroll
      for (int tt = 0; tt < 4; ++tt) {
        int nt = kg * 4 + tt;
        float c2v = c2[nt * 16 + lrow];
#pragma unroll
        for (int j = 0; j < 4; ++j) {
          float x = h1acc[nt][j] + c2v;
          float s = x / (1.f + __expf(-x));  // silu
          sTbuf[wave][tt >> 1][lgrp * 4 + j][(tt & 1) * 16 + lrow] = f2bf(s);
        }
      }
#pragma unroll
      for (int p = 0; p < 2; ++p) {
        bf16x8 hA = *(bf16x8*)&sTbuf[wave][p][lrow][lgrp * 8];
#pragma unroll
        for (int ot = 0; ot < 8; ++ot) {
          bf16x8 w2 = *(bf16x8*)(sStage + kc * 8192 + p * 4096 + ot * 512 + lane8);
          outacc[ot] = mfma16(hA, w2, outacc[ot]);
        }
      }
    }
  }

  // epilogue: out = outacc + b2 (fp32)
#pragma unroll
  for (int ot = 0; ot < 8; ++ot) {
    int col = ot * 16 + lrow;
    float b2v = b2[col];
#pragma unroll
    for (int j = 0; j < 4; ++j)
      Out[(size_t)(r0 + lgrp * 4 + j) * 128 + col] = outacc[ot][j] + b2v;
  }
}

// ---------------------------------------------------------------------------
extern "C" void kernel_launch(void* const* d_in, const int* in_sizes, int n_in,
                              void* d_out, int out_size, void* d_ws, size_t ws_size,
                              hipStream_t stream) {
  const float* Xu = (const float*)d_in[0];
  const float* Xv = (const float*)d_in[1];
  const float* Xe = (const float*)d_in[2];
  const float* Wn = (const float*)d_in[3];
  const float* bn = (const float*)d_in[4];
  const float* We = (const float*)d_in[5];
  const float* be = (const float*)d_in[6];
  const float* Wi = (const float*)d_in[7];
  const float* bi = (const float*)d_in[8];
  const float* Wo = (const float*)d_in[9];
  const float* bo = (const float*)d_in[10];
  const float* W1 = (const float*)d_in[11];
  const float* b1 = (const float*)d_in[12];
  const float* W2 = (const float*)d_in[13];
  const float* b2 = (const float*)d_in[14];

  // ws layout, NO aliasing; total EXACTLY 2,753,536 B (= proven ceiling).
  char* ws = (char*)d_ws;
  float* FT = (float*)(ws + 0);                            // [128,512] f32
  float* P  = (float*)(ws + 262144);                       // [256,512] f32
  float* Kn = (float*)(ws + 786432);                       // [2][256,256]
  float* Ke = (float*)(ws + 1310720);                      // [2][256,128]
  unsigned short* QmT  = (unsigned short*)(ws + 1572864);  // 262144 bf16
  unsigned short* WnvT = (unsigned short*)(ws + 2097152);  // 131072 bf16
  unsigned short* WevT = (unsigned short*)(ws + 2359296);  // 65536 bf16
  unsigned short* MtnT = (unsigned short*)(ws + 2490368);  // 65536 bf16
  unsigned short* MteT = (unsigned short*)(ws + 2621440);  // 32768 bf16
  unsigned short* W2bT = (unsigned short*)(ws + 2686976);  // 32768 bf16
  float* c2 = (float*)(ws + 2752512);                      // [256] f32

  prep1<<<320, 256, 0, stream>>>(Wn, We, Wi, Wo, W1, W2, FT, P, Kn, Ke, WnvT, WevT, W2bT);
  prep2<<<89, 256, 0, stream>>>(Wi, W1, bi, bo, b1, FT, P, Kn, Ke, MtnT, MteT, QmT, c2);
  fused_kernel<<<1024, 128, 0, stream>>>(Xu, Xv, Xe, bn, be, b2, MtnT, MteT, WnvT, WevT, QmT, W2bT,
                                         c2, (float*)d_out);
}

// Round 17
// 171.665 us; speedup vs baseline: 1.2087x; 1.2087x over previous
//
#include <hip/hip_runtime.h>

// MiniAttentionLayer fused kernel for MI355X (gfx950).
//
// ROUND 17: REVERT to R13 (measured best: e2e 171.8us, fused ~119us steady,
// absmax 6.103516e-05). R16's barrier-domain restructure regressed (fused
// 144us: Qm-direct-from-L2 re-exposed per-wave L2 latency; 128-thread blocks
// halved work per staged instruction). Structural map is now complete:
// staging variants equal, barrier re-timing neutral, occupancy capped by
// 144-reg persistent state, finer domains negative. R13 is the keeper.
//
//   score[h,s]*16 = x_e^T M_{h,s} x_s ; softmax -> attn
//   M^n_h = F_h^T @ (Wk_h @ Wn_k) ; M^e_h = F_h^T @ (Wk_h @ We_k) ; F = Wq@We_q
//   vbar_h = sum_s attn[h,s] v_s ; v_s = W*_v x_s (+ b*_v)
//   h1pre = Qm @ [vbar_0|vbar_1] + c2 ; Qm_h = P @ Wv_h ; P = W1@Wo
//   out = W2 @ silu(h1pre) + b2

#define TPB 256

typedef __attribute__((ext_vector_type(8))) short bf16x8;
typedef __attribute__((ext_vector_type(4))) float f32x4;

__device__ __forceinline__ unsigned short f2bf(float f) {
  union { float f; unsigned u; } v; v.f = f;
  unsigned r = v.u + 0x7FFFu + ((v.u >> 16) & 1u);  // RNE
  return (unsigned short)(r >> 16);
}
__device__ __forceinline__ float bf2f(unsigned short h) {
  union { unsigned u; float f; } v; v.u = ((unsigned)h) << 16;
  return v.f;
}
__device__ __forceinline__ f32x4 mfma16(bf16x8 a, bf16x8 b, f32x4 c) {
  return __builtin_amdgcn_mfma_f32_16x16x32_bf16(a, b, c, 0, 0, 0);
}
__device__ __forceinline__ bf16x8 pack8(const float* __restrict__ p) {
  float4 a = *(const float4*)p;
  float4 b = *(const float4*)(p + 4);
  bf16x8 r;
  r[0] = (short)f2bf(a.x); r[1] = (short)f2bf(a.y);
  r[2] = (short)f2bf(a.z); r[3] = (short)f2bf(a.w);
  r[4] = (short)f2bf(b.x); r[5] = (short)f2bf(b.y);
  r[6] = (short)f2bf(b.z); r[7] = (short)f2bf(b.w);
  return r;
}
// fragment-tiled offset: element (lr = B-col within 16-tile, k) -> tiled index
__device__ __forceinline__ int fragoff(int lr, int k) {
  return (k >> 5) * 512 + ((k >> 3) & 3) * 128 + lr * 8 + (k & 7);
}

// LDS-tiled GEMM micro-kernel: 4m x 4n per thread, B staged in 16x128 LDS
// tiles. Bb = B + block n-origin (WITHOUT tn*4); reads B[k][tn*4 + ni].
__device__ __forceinline__ void gemm44s(const float* __restrict__ A0, int lda,
                                        const float* __restrict__ Bb, int ldb,
                                        int K, int tid, int tn,
                                        float (&acc)[4][4], float (*Bs)[132]) {
  for (int k0 = 0; k0 < K; k0 += 16) {
    // stage B[k0..k0+15][0..127] -> Bs (2 float4 per thread, coalesced)
    {
      const int row = tid >> 4;          // 0..15
      const int col = (tid & 15) * 8;    // 0..120
      const float* src = Bb + (size_t)(k0 + row) * ldb + col;
      float4 v0 = *(const float4*)(src);
      float4 v1 = *(const float4*)(src + 4);
      if (k0) __syncthreads();           // prior step's reads done before overwrite
      *(float4*)&Bs[row][col] = v0;
      *(float4*)&Bs[row][col + 4] = v1;
    }
    __syncthreads();
    // A: 4 rows x 16 k, held in registers (broadcast-coalesced loads)
    float a_[4][16];
#pragma unroll
    for (int mi = 0; mi < 4; ++mi)
#pragma unroll
      for (int kq = 0; kq < 4; ++kq) {
        float4 t = *(const float4*)(A0 + mi * lda + k0 + kq * 4);
        a_[mi][kq * 4 + 0] = t.x; a_[mi][kq * 4 + 1] = t.y;
        a_[mi][kq * 4 + 2] = t.z; a_[mi][kq * 4 + 3] = t.w;
      }
#pragma unroll
    for (int kk = 0; kk < 16; ++kk) {
      float4 bv = *(const float4*)&Bs[kk][tn * 4];
#pragma unroll
      for (int mi = 0; mi < 4; ++mi) {
        acc[mi][0] += a_[mi][kk] * bv.x;
        acc[mi][1] += a_[mi][kk] * bv.y;
        acc[mi][2] += a_[mi][kk] * bv.z;
        acc[mi][3] += a_[mi][kk] * bv.w;
      }
    }
  }
}

// ---------------------------------------------------------------------------
// prep1: F->FT ; P = W1@Wo ; Kn_h = Wk_h@Wn_k ; Ke_h = Wk_h@We_k ;
//        WnvT/WevT/W2bT tiled bf16 casts.
// ---------------------------------------------------------------------------
__global__ void prep1(const float* __restrict__ Wn, const float* __restrict__ We,
                      const float* __restrict__ Wi, const float* __restrict__ Wo,
                      const float* __restrict__ W1, const float* __restrict__ W2,
                      float* __restrict__ FT, float* __restrict__ P,
                      float* __restrict__ Kn, float* __restrict__ Ke,
                      unsigned short* __restrict__ WnvT, unsigned short* __restrict__ WevT,
                      unsigned short* __restrict__ W2bT) {
  __shared__ float Bs[16][132];
  const int bid = blockIdx.x, tid = threadIdx.x;
  const int tm = tid >> 5, tn = tid & 31;   // 8 x 32 thread tile
  if (bid < 16) {                           // F [512 m, 128 n] K=512 -> FT[n][m]
    int m = bid * 32 + tm * 4, n0 = tn * 4;
    float acc[4][4] = {};
    gemm44s(Wi + m * 512, 512, We, 128, 512, tid, tn, acc, Bs);
#pragma unroll
    for (int mi = 0; mi < 4; ++mi)
#pragma unroll
      for (int ni = 0; ni < 4; ++ni) FT[(n0 + ni) * 512 + m + mi] = acc[mi][ni];
  } else if (bid < 48) {                    // P [256 m, 512 n] K=512
    int b = bid - 16; int m = (b >> 2) * 32 + tm * 4, n0 = (b & 3) * 128 + tn * 4;
    float acc[4][4] = {};
    gemm44s(W1 + m * 512, 512, Wo + (b & 3) * 128, 512, 512, tid, tn, acc, Bs);
#pragma unroll
    for (int mi = 0; mi < 4; ++mi)
#pragma unroll
      for (int ni = 0; ni < 4; ++ni) P[(m + mi) * 512 + n0 + ni] = acc[mi][ni];
  } else if (bid < 80) {                    // Kn_h [256 c, 256 b] K=512
    int b = bid - 48; int h = b >> 4, r = b & 15;
    int c = (r >> 1) * 32 + tm * 4, b0 = (r & 1) * 128 + tn * 4;
    float acc[4][4] = {};
    gemm44s(Wi + (size_t)(512 + h * 256 + c) * 512, 512, Wn + 512 * 256 + (r & 1) * 128, 256, 512,
            tid, tn, acc, Bs);
#pragma unroll
    for (int mi = 0; mi < 4; ++mi)
#pragma unroll
      for (int ni = 0; ni < 4; ++ni) Kn[h * 65536 + (c + mi) * 256 + b0 + ni] = acc[mi][ni];
  } else if (bid < 96) {                    // Ke_h [256 c, 128 b] K=512
    int b = bid - 80; int h = b >> 3, r = b & 7;
    int c = r * 32 + tm * 4, b0 = tn * 4;
    float acc[4][4] = {};
    gemm44s(Wi + (size_t)(512 + h * 256 + c) * 512, 512, We + 512 * 128, 128, 512, tid, tn, acc, Bs);
#pragma unroll
    for (int mi = 0; mi < 4; ++mi)
#pragma unroll
      for (int ni = 0; ni < 4; ++ni) Ke[h * 32768 + (c + mi) * 128 + b0 + ni] = acc[mi][ni];
  } else if (bid < 224) {                   // Wn_v -> bf16 TILED
    int i = ((bid - 96) * 256 + tid) * 4;
#pragma unroll
    for (int t = 0; t < 4; ++t) {
      int ii = i + t; int vrow = ii >> 8, k = ii & 255;
      WnvT[(vrow >> 4) * 4096 + fragoff(vrow & 15, k)] = f2bf(Wn[262144 + ii]);
    }
  } else if (bid < 288) {                   // We_v -> bf16 TILED
    int i = ((bid - 224) * 256 + tid) * 4;
#pragma unroll
    for (int t = 0; t < 4; ++t) {
      int ii = i + t; int vrow = ii >> 7, k = ii & 127;
      WevT[(vrow >> 4) * 2048 + fragoff(vrow & 15, k)] = f2bf(We[131072 + ii]);
    }
  } else {                                  // W2 -> bf16 TILED
    int i = ((bid - 288) * 256 + tid) * 4;
#pragma unroll
    for (int t = 0; t < 4; ++t) {
      int ii = i + t; int o = ii >> 8, k = ii & 255;
      W2bT[(k >> 6) * 8192 + ((k >> 5) & 1) * 4096 + (o >> 4) * 512 + fragoff(o & 15, k & 31)] =
          f2bf(W2[ii]);
    }
  }
}

// ---------------------------------------------------------------------------
// prep2: MtnT = F_h^T@Kn_h ; MteT = F_h^T@Ke_h ; QmT_h = P_h@Wv_h ; c2.
// ---------------------------------------------------------------------------
__global__ void prep2(const float* __restrict__ Wi, const float* __restrict__ W1,
                      const float* __restrict__ bi, const float* __restrict__ bo,
                      const float* __restrict__ b1,
                      const float* __restrict__ FT, const float* __restrict__ P,
                      const float* __restrict__ Kn, const float* __restrict__ Ke,
                      unsigned short* __restrict__ MtnT, unsigned short* __restrict__ MteT,
                      unsigned short* __restrict__ QmT, float* __restrict__ c2) {
  __shared__ float Bs[16][132];
  const int bid = blockIdx.x, tid = threadIdx.x;
  const int tm = tid >> 5, tn = tid & 31;
  if (bid < 16) {                           // Mtn_h [128 a, 256 b] K=256
    int h = bid >> 3, r = bid & 7;
    int a = (r >> 1) * 32 + tm * 4, b0 = (r & 1) * 128 + tn * 4;
    float acc[4][4] = {};
    gemm44s(FT + a * 512 + h * 256, 512, Kn + h * 65536 + (r & 1) * 128, 256, 256, tid, tn, acc, Bs);
#pragma unroll
    for (int mi = 0; mi < 4; ++mi)
#pragma unroll
      for (int ni = 0; ni < 4; ++ni) {
        int aa = a + mi, bb = b0 + ni;
        MtnT[(h * 2 + (bb >> 7)) * 16384 + ((bb >> 5) & 3) * 4096 + ((bb >> 4) & 1) * 2048 +
             fragoff(bb & 15, aa)] = f2bf(acc[mi][ni]);
      }
  } else if (bid < 24) {                    // Mte_h [128 a, 128 b] K=256
    int b = bid - 16; int h = b >> 2, r = b & 3;
    int a = r * 32 + tm * 4, b0 = tn * 4;
    float acc[4][4] = {};
    gemm44s(FT + a * 512 + h * 256, 512, Ke + h * 32768, 128, 256, tid, tn, acc, Bs);
#pragma unroll
    for (int mi = 0; mi < 4; ++mi)
#pragma unroll
      for (int ni = 0; ni < 4; ++ni) {
        int aa = a + mi, bb = b0 + ni;
        MteT[h * 16384 + ((bb >> 5) & 3) * 4096 + ((bb >> 4) & 1) * 2048 +
             fragoff(bb & 15, aa)] = f2bf(acc[mi][ni]);
      }
  } else if (bid < 88) {                    // Qm_h [256 i, 512 t] K=256
    int b = bid - 24; int h = b >> 5, r = b & 31;
    int i = (r >> 2) * 32 + tm * 4, t0 = (r & 3) * 128 + tn * 4;
    float acc[4][4] = {};
    gemm44s(P + i * 512 + h * 256, 512, Wi + (size_t)(1024 + h * 256) * 512 + (r & 3) * 128, 512,
            256, tid, tn, acc, Bs);
#pragma unroll
    for (int mi = 0; mi < 4; ++mi)
#pragma unroll
      for (int ni = 0; ni < 4; ++ni) {
        int ii = i + mi, tt = t0 + ni;
        QmT[(tt >> 5) * 16384 + h * 8192 + (ii >> 4) * 512 + fragoff(ii & 15, tt & 31)] =
            f2bf(acc[mi][ni]);
      }
  } else {                                  // c2: b1 + P@bv + W1@bo (one block)
    float cc = b1[tid];
    for (int c = 0; c < 512; ++c) cc += P[tid * 512 + c] * bi[1024 + c] + W1[tid * 512 + c] * bo[c];
    c2[tid] = cc;
  }
}

// ---------------------------------------------------------------------------
// Fused kernel helpers (R11 VERBATIM from here down)
// ---------------------------------------------------------------------------
__device__ __forceinline__ void stage32k(unsigned short* lds, const unsigned short* __restrict__ src,
                                         int tid) {
#pragma unroll
  for (int i = 0; i < 8; ++i) {
    int seg = i * 256 + tid;
    *(int4*)(lds + seg * 8) = *(const int4*)(src + seg * 8);
  }
}

template <int AOFS>
__device__ __forceinline__ void p1n(const unsigned short* __restrict__ srcT,
                                    unsigned short* sflat, unsigned short (&tb)[16][40],
                                    const bf16x8 (&au)[8], const bf16x8 (&av)[8],
                                    const bf16x8 (&ae)[4], int tid, int lrow, int lgrp,
                                    float& su, float& sv) {
  stage32k(sflat, srcT, tid);
  __syncthreads();
  const int lane8 = (lgrp * 16 + lrow) * 8;
#pragma unroll
  for (int c = 0; c < 4; ++c) {
    f32x4 acc0 = {0.f, 0.f, 0.f, 0.f}, acc1 = {0.f, 0.f, 0.f, 0.f};
#pragma unroll
    for (int kt = 0; kt < 4; ++kt) {
      bf16x8 b0 = *(bf16x8*)(sflat + c * 4096 + kt * 512 + lane8);
      bf16x8 b1f = *(bf16x8*)(sflat + c * 4096 + 2048 + kt * 512 + lane8);
      acc0 = mfma16(ae[kt], b0, acc0);
      acc1 = mfma16(ae[kt], b1f, acc1);
    }
#pragma unroll
    for (int j = 0; j < 4; ++j) {
      tb[lgrp * 4 + j][lrow] = f2bf(acc0[j]);
      tb[lgrp * 4 + j][16 + lrow] = f2bf(acc1[j]);
    }
    bf16x8 y = *(bf16x8*)&tb[lrow][lgrp * 8];
#pragma unroll
    for (int j = 0; j < 8; ++j) {
      float yf = bf2f((unsigned short)y[j]);
      su += yf * bf2f((unsigned short)au[AOFS + c][j]);
      sv += yf * bf2f((unsigned short)av[AOFS + c][j]);
    }
  }
  __syncthreads();
}

__device__ __forceinline__ void p1e(const unsigned short* __restrict__ srcT,
                                    unsigned short* sflat, unsigned short (&tb)[16][40],
                                    const bf16x8 (&ae)[4], int tid, int lrow, int lgrp,
                                    float& se) {
  stage32k(sflat, srcT, tid);
  __syncthreads();
  const int lane8 = (lgrp * 16 + lrow) * 8;
#pragma unroll
  for (int c = 0; c < 4; ++c) {
    f32x4 acc0 = {0.f, 0.f, 0.f, 0.f}, acc1 = {0.f, 0.f, 0.f, 0.f};
#pragma unroll
    for (int kt = 0; kt < 4; ++kt) {
      bf16x8 b0 = *(bf16x8*)(sflat + c * 4096 + kt * 512 + lane8);
      bf16x8 b1f = *(bf16x8*)(sflat + c * 4096 + 2048 + kt * 512 + lane8);
      acc0 = mfma16(ae[kt], b0, acc0);
      acc1 = mfma16(ae[kt], b1f, acc1);
    }
#pragma unroll
    for (int j = 0; j < 4; ++j) {
      tb[lgrp * 4 + j][lrow] = f2bf(acc0[j]);
      tb[lgrp * 4 + j][16 + lrow] = f2bf(acc1[j]);
    }
    bf16x8 y = *(bf16x8*)&tb[lrow][lgrp * 8];
#pragma unroll
    for (int j = 0; j < 8; ++j)
      se += bf2f((unsigned short)y[j]) * bf2f((unsigned short)ae[c][j]);
  }
  __syncthreads();
}

// ---------------------------------------------------------------------------
// Fused main kernel: 512 blocks x 256 threads (4 waves x 16 rows).
// launch_bounds(256,2); phase-2 loop parity-split. (R11 VERBATIM)
// ---------------------------------------------------------------------------
__global__ __launch_bounds__(TPB, 2) void fused_kernel(
    const float* __restrict__ Xu, const float* __restrict__ Xv, const float* __restrict__ Xe,
    const float* __restrict__ bn, const float* __restrict__ be, const float* __restrict__ b2,
    const unsigned short* __restrict__ MtnT, const unsigned short* __restrict__ MteT,
    const unsigned short* __restrict__ WnvT, const unsigned short* __restrict__ WevT,
    const unsigned short* __restrict__ QmT, const unsigned short* __restrict__ W2bT,
    const float* __restrict__ c2, float* __restrict__ Out) {
  // buf b at sStage + b*14336: Wnv[0,4096) Wev[4096,6144) Qm-half[6144,14336)
  __shared__ unsigned short sStage[28672];          // 56 KB
  __shared__ unsigned short sTbuf[4][2][16][40];    // 10 KB wave-local bounce
  __shared__ float sAttn[4][16][8];                 // 2 KB

  const int tid = threadIdx.x;
  const int wave = tid >> 6;
  const int lane = tid & 63;
  const int lrow = lane & 15, lgrp = lane >> 4;
  const int lane8 = lane * 8;
  const int r0 = blockIdx.x * 64 + wave * 16;

  // ---- A fragments (rows of this wave), fp32 -> bf16 ----
  bf16x8 au[8], av[8], ae[4];
  {
    const float* xu = Xu + (size_t)(r0 + lrow) * 256;
    const float* xv = Xv + (size_t)(r0 + lrow) * 256;
    const float* xe = Xe + (size_t)(r0 + lrow) * 128;
#pragma unroll
    for (int kt = 0; kt < 8; ++kt) {
      int off = kt * 32 + lgrp * 8;
      au[kt] = pack8(xu + off);
      av[kt] = pack8(xv + off);
    }
#pragma unroll
    for (int kt = 0; kt < 4; ++kt) ae[kt] = pack8(xe + kt * 32 + lgrp * 8);
  }

  // ================= Phase 1: scores (6 staged 32KB slices) =================
  float su0 = 0.f, sv0 = 0.f, se0 = 0.f, su1 = 0.f, sv1 = 0.f, se1 = 0.f;
  p1n<0>(MtnT,          sStage, sTbuf[wave][0], au, av, ae, tid, lrow, lgrp, su0, sv0);
  p1n<4>(MtnT + 16384,  sStage, sTbuf[wave][0], au, av, ae, tid, lrow, lgrp, su0, sv0);
  p1n<0>(MtnT + 32768,  sStage, sTbuf[wave][0], au, av, ae, tid, lrow, lgrp, su1, sv1);
  p1n<4>(MtnT + 49152,  sStage, sTbuf[wave][0], au, av, ae, tid, lrow, lgrp, su1, sv1);
  p1e(MteT,          sStage, sTbuf[wave][0], ae, tid, lrow, lgrp, se0);
  p1e(MteT + 16384,  sStage, sTbuf[wave][0], ae, tid, lrow, lgrp, se1);

  su0 += __shfl_xor(su0, 16); su0 += __shfl_xor(su0, 32);
  sv0 += __shfl_xor(sv0, 16); sv0 += __shfl_xor(sv0, 32);
  se0 += __shfl_xor(se0, 16); se0 += __shfl_xor(se0, 32);
  su1 += __shfl_xor(su1, 16); su1 += __shfl_xor(su1, 32);
  sv1 += __shfl_xor(sv1, 16); sv1 += __shfl_xor(sv1, 32);
  se1 += __shfl_xor(se1, 16); se1 += __shfl_xor(se1, 32);
  if (lane < 16) {
    sAttn[wave][lrow][0] = su0; sAttn[wave][lrow][1] = sv0; sAttn[wave][lrow][2] = se0;
    sAttn[wave][lrow][3] = su1; sAttn[wave][lrow][4] = sv1; sAttn[wave][lrow][5] = se1;
  }
  // softmax over s (scale 1/16); wave-local
  if (lane < 16) {
#pragma unroll
    for (int h = 0; h < 2; ++h) {
      float s0 = sAttn[wave][lrow][h * 3 + 0] * 0.0625f;
      float s1 = sAttn[wave][lrow][h * 3 + 1] * 0.0625f;
      float s2 = sAttn[wave][lrow][h * 3 + 2] * 0.0625f;
      float m = fmaxf(s0, fmaxf(s1, s2));
      float e0 = __expf(s0 - m), e1 = __expf(s1 - m), e2 = __expf(s2 - m);
      float inv = 1.f / (e0 + e1 + e2);
      sAttn[wave][lrow][h * 3 + 0] = e0 * inv;
      sAttn[wave][lrow][h * 3 + 1] = e1 * inv;
      sAttn[wave][lrow][h * 3 + 2] = e2 * inv;
    }
  }

  // ================= Phase 2: v-GEMM + vbar + Q-GEMM, 32 chunks =============
  f32x4 h1acc[16];
#pragma unroll
  for (int i = 0; i < 16; ++i) h1acc[i] = (f32x4){0.f, 0.f, 0.f, 0.f};

  // prologue: buf0 = {Wnv(0), Wev(0), Qm pair0 half1}
  {
#pragma unroll
    for (int i = 0; i < 7; ++i) {
      int seg = i * 256 + tid;
      int4 v;
      if (i < 2)       v = *(const int4*)(WnvT + seg * 8);
      else if (i == 2) v = *(const int4*)(WevT + (seg - 512) * 8);
      else             v = *(const int4*)(QmT + 8192 + (seg - 768) * 8);
      *(int4*)(sStage + seg * 8) = v;
    }
  }
  __syncthreads();

#pragma unroll 1
  for (int t2 = 0; t2 < 16; ++t2) {
    // ========== EVEN t = 2*t2 : wb = buf0, nb = buf1 ==========
    {
      const int t = 2 * t2;
      unsigned short* wb = sStage;
      unsigned short* nb = sStage + 14336;
      const int cn = t + 1;                 // next chunk (<=31)
      // stage A: Wnv/Wev of chunk t+1 (12 regs)
      int4 st0 = *(const int4*)(WnvT + cn * 4096 + tid * 8);
      int4 st1 = *(const int4*)(WnvT + cn * 4096 + (256 + tid) * 8);
      int4 st2 = *(const int4*)(WevT + cn * 2048 + tid * 8);

      // v-GEMM on wb
      f32x4 vu = {0.f, 0.f, 0.f, 0.f}, vv = {0.f, 0.f, 0.f, 0.f}, ve = {0.f, 0.f, 0.f, 0.f};
#pragma unroll
      for (int kt = 0; kt < 8; ++kt) {
        bf16x8 b = *(bf16x8*)(wb + kt * 512 + lane8);
        vu = mfma16(au[kt], b, vu);
        vv = mfma16(av[kt], b, vv);
      }
#pragma unroll
      for (int kt = 0; kt < 4; ++kt) {
        bf16x8 b = *(bf16x8*)(wb + 4096 + kt * 512 + lane8);
        ve = mfma16(ae[kt], b, ve);
      }
      // write Wnv/Wev -> nb (buf1 is read by nobody during even t)
      *(int4*)(nb + tid * 8) = st0;
      *(int4*)(nb + (256 + tid) * 8) = st1;
      *(int4*)(nb + (512 + tid) * 8) = st2;

      // stage B: Qm pair t2 half0 (16 regs; latency covered by combine)
      const int qoff = t2 * 16384;
      int4 st3 = *(const int4*)(QmT + qoff + tid * 8);
      int4 st4 = *(const int4*)(QmT + qoff + (256 + tid) * 8);
      int4 st5 = *(const int4*)(QmT + qoff + (512 + tid) * 8);
      int4 st6 = *(const int4*)(QmT + qoff + (768 + tid) * 8);

      // combine -> sTbuf (cur=0 -> col offset 0)
      const int vrow = t * 16 + lrow;
      const float bnv = bn[1024 + vrow], bev = be[1024 + vrow];
#pragma unroll
      for (int j = 0; j < 4; ++j) {
        const float* ar = &sAttn[wave][lgrp * 4 + j][0];
#pragma unroll
        for (int h = 0; h < 2; ++h) {
          float a0 = ar[h * 3 + 0], a1 = ar[h * 3 + 1], a2 = ar[h * 3 + 2];
          float vb = a0 * vu[j] + a1 * vv[j] + a2 * ve[j] + (a0 + a1) * bnv + a2 * bev;
          sTbuf[wave][h][lgrp * 4 + j][lrow] = f2bf(vb);
        }
      }
      // write Qm -> nb
      *(int4*)(nb + (768 + tid) * 8) = st3;
      *(int4*)(nb + (1024 + tid) * 8) = st4;
      *(int4*)(nb + (1280 + tid) * 8) = st5;
      *(int4*)(nb + (1536 + tid) * 8) = st6;
      __syncthreads();
    }
    // ========== ODD t = 2*t2+1 : wb = buf1, nb = buf0 ==========
    {
      const int t = 2 * t2 + 1;
      unsigned short* wb = sStage + 14336;
      unsigned short* nb = sStage;
      const bool last = (t2 == 15);
      const int cn = t + 1;

      // stage A: Wnv/Wev of chunk t+1 (skip on last)
      int4 st0, st1, st2;
      if (!last) {
        st0 = *(const int4*)(WnvT + cn * 4096 + tid * 8);
        st1 = *(const int4*)(WnvT + cn * 4096 + (256 + tid) * 8);
        st2 = *(const int4*)(WevT + cn * 2048 + tid * 8);
      }

      // v-GEMM on wb
      f32x4 vu = {0.f, 0.f, 0.f, 0.f}, vv = {0.f, 0.f, 0.f, 0.f}, ve = {0.f, 0.f, 0.f, 0.f};
#pragma unroll
      for (int kt = 0; kt < 8; ++kt) {
        bf16x8 b = *(bf16x8*)(wb + kt * 512 + lane8);
        vu = mfma16(au[kt], b, vu);
        vv = mfma16(av[kt], b, vv);
      }
#pragma unroll
      for (int kt = 0; kt < 4; ++kt) {
        bf16x8 b = *(bf16x8*)(wb + 4096 + kt * 512 + lane8);
        ve = mfma16(ae[kt], b, ve);
      }
      // write Wnv/Wev -> nb (buf0's Wnv/Wev slots unread during odd t)
      if (!last) {
        *(int4*)(nb + tid * 8) = st0;
        *(int4*)(nb + (256 + tid) * 8) = st1;
        *(int4*)(nb + (512 + tid) * 8) = st2;
      }

      // stage B: Qm pair t2+1 half1 (latency covered by combine + Q-GEMM)
      int4 st3, st4, st5, st6;
      if (!last) {
        const int qoff = (t2 + 1) * 16384 + 8192;
        st3 = *(const int4*)(QmT + qoff + tid * 8);
        st4 = *(const int4*)(QmT + qoff + (256 + tid) * 8);
        st5 = *(const int4*)(QmT + qoff + (512 + tid) * 8);
        st6 = *(const int4*)(QmT + qoff + (768 + tid) * 8);
      }

      // combine -> sTbuf (cur=1 -> col offset 16)
      const int vrow = t * 16 + lrow;
      const float bnv = bn[1024 + vrow], bev = be[1024 + vrow];
#pragma unroll
      for (int j = 0; j < 4; ++j) {
        const float* ar = &sAttn[wave][lgrp * 4 + j][0];
#pragma unroll
        for (int h = 0; h < 2; ++h) {
          float a0 = ar[h * 3 + 0], a1 = ar[h * 3 + 1], a2 = ar[h * 3 + 2];
          float vb = a0 * vu[j] + a1 * vv[j] + a2 * ve[j] + (a0 + a1) * bnv + a2 * bev;
          sTbuf[wave][h][lgrp * 4 + j][16 + lrow] = f2bf(vb);
        }
      }

      // Q-GEMM over the completed 32-col pair: h2=0 from wb, h2=1 from nb
#pragma unroll
      for (int h2 = 0; h2 < 2; ++h2) {
        const unsigned short* qb = (h2 == 0 ? wb : nb) + 6144;
        bf16x8 vbx = *(bf16x8*)&sTbuf[wave][h2][lrow][lgrp * 8];
#pragma unroll
        for (int nt = 0; nt < 16; ++nt) {
          bf16x8 bq = *(bf16x8*)(qb + nt * 512 + lane8);
          h1acc[nt] = mfma16(vbx, bq, h1acc[nt]);
        }
      }
      __syncthreads();  // all waves done reading nb's Qm slot before overwrite
      if (!last) {
        *(int4*)(nb + (768 + tid) * 8) = st3;
        *(int4*)(nb + (1024 + tid) * 8) = st4;
        *(int4*)(nb + (1280 + tid) * 8) = st5;
        *(int4*)(nb + (1536 + tid) * 8) = st6;
      }
      __syncthreads();
    }
  }

  // ================= Phase 3: silu + W2 (2 staged 32KB halves) ==============
  f32x4 outacc[8];
#pragma unroll
  for (int i = 0; i < 8; ++i) outacc[i] = (f32x4){0.f, 0.f, 0.f, 0.f};

#pragma unroll
  for (int hh = 0; hh < 2; ++hh) {
    if (hh) __syncthreads();  // protect previous half's reads
    stage32k(sStage, W2bT + hh * 16384, tid);
    __syncthreads();
#pragma unroll
    for (int kc = 0; kc < 2; ++kc) {
      const int kg = hh * 2 + kc;
#pragma unroll
      for (int tt = 0; tt < 4; ++tt) {
        int nt = kg * 4 + tt;
        float c2v = c2[nt * 16 + lrow];
#pragma unroll
        for (int j = 0; j < 4; ++j) {
          float x = h1acc[nt][j] + c2v;
          float s = x / (1.f + __expf(-x));  // silu
          sTbuf[wave][tt >> 1][lgrp * 4 + j][(tt & 1) * 16 + lrow] = f2bf(s);
        }
      }
#pragma unroll
      for (int p = 0; p < 2; ++p) {
        bf16x8 hA = *(bf16x8*)&sTbuf[wave][p][lrow][lgrp * 8];
#pragma unroll
        for (int ot = 0; ot < 8; ++ot) {
          bf16x8 w2 = *(bf16x8*)(sStage + kc * 8192 + p * 4096 + ot * 512 + lane8);
          outacc[ot] = mfma16(hA, w2, outacc[ot]);
        }
      }
    }
  }

  // epilogue: out = outacc + b2 (fp32)
#pragma unroll
  for (int ot = 0; ot < 8; ++ot) {
    int col = ot * 16 + lrow;
    float b2v = b2[col];
#pragma unroll
    for (int j = 0; j < 4; ++j)
      Out[(size_t)(r0 + lgrp * 4 + j) * 128 + col] = outacc[ot][j] + b2v;
  }
}

// ---------------------------------------------------------------------------
extern "C" void kernel_launch(void* const* d_in, const int* in_sizes, int n_in,
                              void* d_out, int out_size, void* d_ws, size_t ws_size,
                              hipStream_t stream) {
  const float* Xu = (const float*)d_in[0];
  const float* Xv = (const float*)d_in[1];
  const float* Xe = (const float*)d_in[2];
  const float* Wn = (const float*)d_in[3];
  const float* bn = (const float*)d_in[4];
  const float* We = (const float*)d_in[5];
  const float* be = (const float*)d_in[6];
  const float* Wi = (const float*)d_in[7];
  const float* bi = (const float*)d_in[8];
  const float* Wo = (const float*)d_in[9];
  const float* bo = (const float*)d_in[10];
  const float* W1 = (const float*)d_in[11];
  const float* b1 = (const float*)d_in[12];
  const float* W2 = (const float*)d_in[13];
  const float* b2 = (const float*)d_in[14];

  // ws layout, NO aliasing; total EXACTLY 2,753,536 B (= proven ceiling).
  char* ws = (char*)d_ws;
  float* FT = (float*)(ws + 0);                            // [128,512] f32
  float* P  = (float*)(ws + 262144);                       // [256,512] f32
  float* Kn = (float*)(ws + 786432);                       // [2][256,256]
  float* Ke = (float*)(ws + 1310720);                      // [2][256,128]
  unsigned short* QmT  = (unsigned short*)(ws + 1572864);  // 262144 bf16
  unsigned short* WnvT = (unsigned short*)(ws + 2097152);  // 131072 bf16
  unsigned short* WevT = (unsigned short*)(ws + 2359296);  // 65536 bf16
  unsigned short* MtnT = (unsigned short*)(ws + 2490368);  // 65536 bf16
  unsigned short* MteT = (unsigned short*)(ws + 2621440);  // 32768 bf16
  unsigned short* W2bT = (unsigned short*)(ws + 2686976);  // 32768 bf16
  float* c2 = (float*)(ws + 2752512);                      // [256] f32

  prep1<<<320, 256, 0, stream>>>(Wn, We, Wi, Wo, W1, W2, FT, P, Kn, Ke, WnvT, WevT, W2bT);
  prep2<<<89, 256, 0, stream>>>(Wi, W1, bi, bo, b1, FT, P, Kn, Ke, MtnT, MteT, QmT, c2);
  fused_kernel<<<512, 256, 0, stream>>>(Xu, Xv, Xe, bn, be, b2, MtnT, MteT, WnvT, WevT, QmT, W2bT,
                                        c2, (float*)d_out);
}